// Round 1
// baseline (1554.803 us; speedup 1.0000x reference)
//
#include <hip/hip_runtime.h>
#include <hip/hip_fp16.h>

#define B_  32
#define T_  2048
#define I_  256
#define H_  128

typedef _Float16 f16;
typedef _Float16 f16x2 __attribute__((ext_vector_type(2)));
typedef _Float16 f16x4 __attribute__((ext_vector_type(4)));
typedef _Float16 f16x8 __attribute__((ext_vector_type(8)));
typedef float    f32x4 __attribute__((ext_vector_type(4)));

#if __has_builtin(__builtin_amdgcn_fdot2)
#define FDOT2(a, b, c) __builtin_amdgcn_fdot2((a), (b), (c), false)
#else
static __device__ __forceinline__ float FDOT2(f16x2 a, f16x2 b, float c) {
  return c + (float)a[0] * (float)b[0] + (float)a[1] * (float)b[1];
}
#endif

static __device__ __forceinline__ f16x2 asf16x2(unsigned u) {
  return __builtin_bit_cast(f16x2, u);
}

// sigmoid(x) = 1/(1+2^(-x*log2e));  tanh(x) = 2/(1+2^(-2x*log2e)) - 1
static __device__ __forceinline__ float fast_sig(float x) {
  float e = __builtin_amdgcn_exp2f(-1.44269504089f * x);
  return __builtin_amdgcn_rcpf(1.0f + e);
}
static __device__ __forceinline__ float fast_tanh(float x) {
  float e = __builtin_amdgcn_exp2f(-2.88539008178f * x);
  return 2.0f * __builtin_amdgcn_rcpf(1.0f + e) - 1.0f;
}

// ---------------------------------------------------------------------------
// Kernel 1: xg[m][n] = sum_k x[m][k] * W'[n][k] + b_ih[n] + b_hh[n]
//   m = b*T+t (65536 rows), n in [0,1024): n<512 fwd gates, n>=512 bwd gates.
//   Output f16 to workspace.  BM=128, BN=128, K=256 single-shot in LDS.
// ---------------------------------------------------------------------------
__global__ __launch_bounds__(256) void xg_gemm(
    const float* __restrict__ x,
    const float* __restrict__ Wf, const float* __restrict__ Wb,
    const float* __restrict__ bf_ih, const float* __restrict__ bf_hh,
    const float* __restrict__ bb_ih, const float* __restrict__ bb_hh,
    f16* __restrict__ xg)
{
  __shared__ f16 xs[128][264];   // +8 f16 pad -> 528B row pitch, conflict-light
  __shared__ f16 wt[128][264];

  const int tid = threadIdx.x;
  const int m0  = blockIdx.y * 128;
  const int n0  = blockIdx.x * 128;

  const float* Wsrc; const float* bih; const float* bhh; int nb;
  if (n0 < 512) { Wsrc = Wf; bih = bf_ih; bhh = bf_hh; nb = n0; }
  else          { Wsrc = Wb; bih = bb_ih; bhh = bb_hh; nb = n0 - 512; }

  // stage x tile (128x256 f32 -> f16), coalesced float4 loads
  #pragma unroll
  for (int it = 0; it < 32; ++it) {
    int idx = it * 256 + tid;
    int row = idx >> 6, c4 = idx & 63;
    float4 v = *(const float4*)&x[(size_t)(m0 + row) * I_ + c4 * 4];
    f16x4 h4 = { (f16)v.x, (f16)v.y, (f16)v.z, (f16)v.w };
    *(f16x4*)&xs[row][c4 * 4] = h4;
  }
  // stage W tile (rows nb..nb+127 of the selected direction's W_ih)
  #pragma unroll
  for (int it = 0; it < 32; ++it) {
    int idx = it * 256 + tid;
    int row = idx >> 6, c4 = idx & 63;
    float4 v = *(const float4*)&Wsrc[(size_t)(nb + row) * I_ + c4 * 4];
    f16x4 h4 = { (f16)v.x, (f16)v.y, (f16)v.z, (f16)v.w };
    *(f16x4*)&wt[row][c4 * 4] = h4;
  }
  __syncthreads();

  const int w  = tid >> 6;           // wave 0..3 -> rows [32w, 32w+32)
  const int l  = tid & 63;
  const int lr = l & 15;
  const int lk = (l >> 4) * 8;

  f32x4 acc[2][8] = {};
  #pragma unroll
  for (int ks = 0; ks < 8; ++ks) {
    int kk = ks * 32 + lk;
    f16x8 a0 = *(const f16x8*)&xs[w * 32 + lr][kk];
    f16x8 a1 = *(const f16x8*)&xs[w * 32 + 16 + lr][kk];
    #pragma unroll
    for (int nt = 0; nt < 8; ++nt) {
      f16x8 bf = *(const f16x8*)&wt[nt * 16 + lr][kk];
      acc[0][nt] = __builtin_amdgcn_mfma_f32_16x16x32_f16(a0, bf, acc[0][nt], 0, 0, 0);
      acc[1][nt] = __builtin_amdgcn_mfma_f32_16x16x32_f16(a1, bf, acc[1][nt], 0, 0, 0);
    }
  }

  // epilogue: D row = (l>>4)*4 + r, col = l&15 (m89-verified layout)
  #pragma unroll
  for (int mt = 0; mt < 2; ++mt) {
    #pragma unroll
    for (int nt = 0; nt < 8; ++nt) {
      int nloc = nt * 16 + lr;
      float bias = bih[nb + nloc] + bhh[nb + nloc];
      #pragma unroll
      for (int r = 0; r < 4; ++r) {
        int m = m0 + w * 32 + mt * 16 + (l >> 4) * 4 + r;
        xg[(size_t)m * 1024 + n0 + nloc] = (f16)(acc[mt][nt][r] + bias);
      }
    }
  }
}

// ---------------------------------------------------------------------------
// Kernel 2: the recurrence. One 256-thread WG per (dir, batch) = 64 WGs.
//   Thread t owns gate rows {t, t+256}: t<128 -> (i,g) of unit t;
//   t>=128 -> (f,o) of unit t-128.  W_hh rows live in registers as f16 pairs.
//   h broadcast via LDS f16 buffer (double-buffered); c stays in registers.
// ---------------------------------------------------------------------------
__global__ __launch_bounds__(256, 1) void birnn_rec(
    const f16* __restrict__ xg,
    const float* __restrict__ Wfhh, const float* __restrict__ Wbhh,
    const int* __restrict__ lengths,
    float* __restrict__ out)
{
  const int tid = threadIdx.x;
  const int dir = blockIdx.x >> 5;
  const int b   = blockIdx.x & 31;
  const float* Whh = dir ? Wbhh : Wfhh;
  const int g0 = tid, g1 = tid + 256;
  const int L  = lengths[b];

  // W_hh rows g0,g1 -> f16x2 register arrays (fully unrolled: static indices)
  unsigned w0[64], w1[64];
  #pragma unroll
  for (int j = 0; j < 32; ++j) {
    float4 v = *(const float4*)&Whh[(size_t)g0 * H_ + j * 4];
    w0[2 * j]     = __builtin_bit_cast(unsigned, (f16x2){ (f16)v.x, (f16)v.y });
    w0[2 * j + 1] = __builtin_bit_cast(unsigned, (f16x2){ (f16)v.z, (f16)v.w });
    float4 u = *(const float4*)&Whh[(size_t)g1 * H_ + j * 4];
    w1[2 * j]     = __builtin_bit_cast(unsigned, (f16x2){ (f16)u.x, (f16)u.y });
    w1[2 * j + 1] = __builtin_bit_cast(unsigned, (f16x2){ (f16)u.z, (f16)u.w });
  }

  __shared__ __align__(16) unsigned hbuf[2][64];  // h as f16x2 words, dbuf
  __shared__ float gx[512];                       // gate exchange (f,o crossing)

  if (tid < 64) { hbuf[0][tid] = 0u; }
  float c = 0.0f;
  __syncthreads();

  auto rowof = [&](int t) -> size_t {
    int it = t;
    if (dir) it = (t < L) ? (L - 1 - t) : t;
    return ((size_t)(b * T_ + it)) * 1024 + (size_t)dir * 512;
  };

  // depth-2 xg prefetch, named slots (no runtime-indexed register arrays)
  f16 pa0, pa1, pb0, pb1;
  { size_t r = rowof(0); pa0 = xg[r + g0]; pa1 = xg[r + g1]; }
  { size_t r = rowof(1); pb0 = xg[r + g0]; pb1 = xg[r + g1]; }

#define STEP(t, P0, P1, HR, HW)                                              \
  {                                                                          \
    float acc0 = (float)(P0);                                                \
    float acc1 = (float)(P1);                                                \
    if ((t) + 2 < T_) {                                                      \
      size_t r2 = rowof((t) + 2);                                            \
      (P0) = xg[r2 + g0];                                                    \
      (P1) = xg[r2 + g1];                                                    \
    }                                                                        \
    _Pragma("unroll")                                                        \
    for (int j4 = 0; j4 < 16; ++j4) {                                        \
      uint4 hv = *(const uint4*)&(HR)[j4 * 4];                               \
      acc0 = FDOT2(asf16x2(hv.x), asf16x2(w0[j4 * 4 + 0]), acc0);            \
      acc1 = FDOT2(asf16x2(hv.x), asf16x2(w1[j4 * 4 + 0]), acc1);            \
      acc0 = FDOT2(asf16x2(hv.y), asf16x2(w0[j4 * 4 + 1]), acc0);            \
      acc1 = FDOT2(asf16x2(hv.y), asf16x2(w1[j4 * 4 + 1]), acc1);            \
      acc0 = FDOT2(asf16x2(hv.z), asf16x2(w0[j4 * 4 + 2]), acc0);            \
      acc1 = FDOT2(asf16x2(hv.z), asf16x2(w1[j4 * 4 + 2]), acc1);            \
      acc0 = FDOT2(asf16x2(hv.w), asf16x2(w0[j4 * 4 + 3]), acc0);            \
      acc1 = FDOT2(asf16x2(hv.w), asf16x2(w1[j4 * 4 + 3]), acc1);            \
    }                                                                        \
    if (tid >= 128) { gx[tid] = acc0; gx[tid + 256] = acc1; }                \
    __syncthreads();                                                         \
    if (tid < 128) {                                                         \
      float ff = gx[128 + tid];                                              \
      float oo = gx[384 + tid];                                              \
      float is = fast_sig(acc0);                                             \
      float gt = fast_tanh(acc1);                                            \
      float fs = fast_sig(ff);                                               \
      float os = fast_sig(oo);                                               \
      c = fs * c + is * gt;                                                  \
      float hval = os * fast_tanh(c);                                        \
      ((unsigned short*)(HW))[tid] =                                         \
          __builtin_bit_cast(unsigned short, (f16)hval);                     \
      out[((size_t)(b * T_ + (t))) * 256 + dir * 128 + tid] = hval;          \
    }                                                                        \
    __syncthreads();                                                         \
  }

  for (int tt = 0; tt < T_; tt += 2) {
    STEP(tt,     pa0, pa1, hbuf[0], hbuf[1]);
    STEP(tt + 1, pb0, pb1, hbuf[1], hbuf[0]);
  }
#undef STEP
}

// ---------------------------------------------------------------------------
extern "C" void kernel_launch(void* const* d_in, const int* in_sizes, int n_in,
                              void* d_out, int out_size, void* d_ws, size_t ws_size,
                              hipStream_t stream) {
  const float* x      = (const float*)d_in[0];
  const int*   lengths= (const int*)  d_in[1];
  const float* Wf_ih  = (const float*)d_in[2];
  const float* Wf_hh  = (const float*)d_in[3];
  const float* bf_ih  = (const float*)d_in[4];
  const float* bf_hh  = (const float*)d_in[5];
  const float* Wb_ih  = (const float*)d_in[6];
  const float* Wb_hh  = (const float*)d_in[7];
  const float* bb_ih  = (const float*)d_in[8];
  const float* bb_hh  = (const float*)d_in[9];
  float* out = (float*)d_out;
  f16*   xg  = (f16*)d_ws;   // needs B*T*1024*2 = 134,217,728 bytes

  (void)in_sizes; (void)n_in; (void)out_size; (void)ws_size;

  xg_gemm<<<dim3(8, 512), 256, 0, stream>>>(x, Wf_ih, Wb_ih,
                                            bf_ih, bf_hh, bb_ih, bb_hh, xg);
  birnn_rec<<<dim3(64), 256, 0, stream>>>(xg, Wf_hh, Wb_hh, lengths, out);
}

// Round 2
// 1352.431 us; speedup vs baseline: 1.1496x; 1.1496x over previous
//
#include <hip/hip_runtime.h>
#include <hip/hip_fp16.h>

#define B_  32
#define T_  2048
#define I_  256
#define H_  128

typedef _Float16 f16;
typedef _Float16 f16x2 __attribute__((ext_vector_type(2)));
typedef _Float16 f16x4 __attribute__((ext_vector_type(4)));
typedef _Float16 f16x8 __attribute__((ext_vector_type(8)));
typedef float    f32x4 __attribute__((ext_vector_type(4)));

#if __has_builtin(__builtin_amdgcn_fdot2)
#define FDOT2(a, b, c) __builtin_amdgcn_fdot2((a), (b), (c), false)
#else
static __device__ __forceinline__ float FDOT2(f16x2 a, f16x2 b, float c) {
  return c + (float)a[0] * (float)b[0] + (float)a[1] * (float)b[1];
}
#endif

static __device__ __forceinline__ f16x2 asf16x2(unsigned u) {
  return __builtin_bit_cast(f16x2, u);
}

// sigmoid(x) = 1/(1+2^(-x*log2e));  tanh(x) = 2/(1+2^(-2x*log2e)) - 1
static __device__ __forceinline__ float fast_sig(float x) {
  float e = __builtin_amdgcn_exp2f(-1.44269504089f * x);
  return __builtin_amdgcn_rcpf(1.0f + e);
}
static __device__ __forceinline__ float fast_tanh(float x) {
  float e = __builtin_amdgcn_exp2f(-2.88539008178f * x);
  return 2.0f * __builtin_amdgcn_rcpf(1.0f + e) - 1.0f;
}

// LDS-only barrier: do NOT drain vmcnt -- global prefetch loads and out[]
// stores float across steps.  sched_barrier(0) fences per rule #18.
#define BARRIER_LDS()                                   \
  __builtin_amdgcn_sched_barrier(0);                    \
  asm volatile("s_waitcnt lgkmcnt(0)" ::: "memory");    \
  __builtin_amdgcn_s_barrier();                         \
  __builtin_amdgcn_sched_barrier(0)

// ---------------------------------------------------------------------------
// Kernel 1: xg[m][n] = sum_k x[m][k] * W'[n][k] + b_ih[n] + b_hh[n]
//   m = b*T+t (65536 rows), n in [0,1024): n<512 fwd gates, n>=512 bwd gates.
//   Output f16 to workspace.  BM=128, BN=128; K staged in two 128-halves so
//   LDS = 69 KB -> 2 WGs/CU (was 135 KB -> 1 WG/CU).
// ---------------------------------------------------------------------------
__global__ __launch_bounds__(256) void xg_gemm(
    const float* __restrict__ x,
    const float* __restrict__ Wf, const float* __restrict__ Wb,
    const float* __restrict__ bf_ih, const float* __restrict__ bf_hh,
    const float* __restrict__ bb_ih, const float* __restrict__ bb_hh,
    f16* __restrict__ xg)
{
  __shared__ f16 xs[128][136];   // +8 f16 pad
  __shared__ f16 wt[128][136];

  const int tid = threadIdx.x;
  const int m0  = blockIdx.y * 128;
  const int n0  = blockIdx.x * 128;

  const float* Wsrc; const float* bih; const float* bhh; int nb;
  if (n0 < 512) { Wsrc = Wf; bih = bf_ih; bhh = bf_hh; nb = n0; }
  else          { Wsrc = Wb; bih = bb_ih; bhh = bb_hh; nb = n0 - 512; }

  const int w  = tid >> 6;           // wave 0..3 -> rows [32w, 32w+32)
  const int l  = tid & 63;
  const int lr = l & 15;
  const int lk = (l >> 4) * 8;

  f32x4 acc[2][8] = {};

  #pragma unroll
  for (int kh = 0; kh < 2; ++kh) {
    // stage x tile half (128 rows x 128 cols f32 -> f16), coalesced float4
    #pragma unroll
    for (int it = 0; it < 16; ++it) {
      int idx = it * 256 + tid;
      int row = idx >> 5, c4 = idx & 31;
      float4 v = *(const float4*)&x[(size_t)(m0 + row) * I_ + kh * 128 + c4 * 4];
      f16x4 h4 = { (f16)v.x, (f16)v.y, (f16)v.z, (f16)v.w };
      *(f16x4*)&xs[row][c4 * 4] = h4;
    }
    // stage W tile half
    #pragma unroll
    for (int it = 0; it < 16; ++it) {
      int idx = it * 256 + tid;
      int row = idx >> 5, c4 = idx & 31;
      float4 v = *(const float4*)&Wsrc[(size_t)(nb + row) * I_ + kh * 128 + c4 * 4];
      f16x4 h4 = { (f16)v.x, (f16)v.y, (f16)v.z, (f16)v.w };
      *(f16x4*)&wt[row][c4 * 4] = h4;
    }
    __syncthreads();

    #pragma unroll
    for (int ks = 0; ks < 4; ++ks) {
      int kk = ks * 32 + lk;
      f16x8 a0 = *(const f16x8*)&xs[w * 32 + lr][kk];
      f16x8 a1 = *(const f16x8*)&xs[w * 32 + 16 + lr][kk];
      #pragma unroll
      for (int nt = 0; nt < 8; ++nt) {
        f16x8 bf = *(const f16x8*)&wt[nt * 16 + lr][kk];
        acc[0][nt] = __builtin_amdgcn_mfma_f32_16x16x32_f16(a0, bf, acc[0][nt], 0, 0, 0);
        acc[1][nt] = __builtin_amdgcn_mfma_f32_16x16x32_f16(a1, bf, acc[1][nt], 0, 0, 0);
      }
    }
    __syncthreads();
  }

  // epilogue: D row = (l>>4)*4 + r, col = l&15 (m89-verified layout)
  #pragma unroll
  for (int mt = 0; mt < 2; ++mt) {
    #pragma unroll
    for (int nt = 0; nt < 8; ++nt) {
      int nloc = nt * 16 + lr;
      float bias = bih[nb + nloc] + bhh[nb + nloc];
      #pragma unroll
      for (int r = 0; r < 4; ++r) {
        int m = m0 + w * 32 + mt * 16 + (l >> 4) * 4 + r;
        xg[(size_t)m * 1024 + n0 + nloc] = (f16)(acc[mt][nt][r] + bias);
      }
    }
  }
}

// ---------------------------------------------------------------------------
// Kernel 2: the recurrence. One 256-thread WG per (dir, batch) = 64 WGs.
//   Thread t owns gate rows {t, t+256}: t<128 -> (i,g) of unit t;
//   t>=128 -> (f,o) of unit t-128.  W_hh rows live in registers as f16 pairs.
//   h broadcast via LDS f16 buffer (double-buffered); c stays in registers.
//   Barriers are LDS-only (no vmcnt drain); 4 accumulator chains per gate;
//   producers pre-apply sigmoid to f,o before the LDS exchange.
// ---------------------------------------------------------------------------
__global__ __launch_bounds__(256, 1) void birnn_rec(
    const f16* __restrict__ xg,
    const float* __restrict__ Wfhh, const float* __restrict__ Wbhh,
    const int* __restrict__ lengths,
    float* __restrict__ out)
{
  const int tid = threadIdx.x;
  const int dir = blockIdx.x >> 5;
  const int b   = blockIdx.x & 31;
  const float* Whh = dir ? Wbhh : Wfhh;
  const int g0 = tid, g1 = tid + 256;
  const int L  = lengths[b];

  // W_hh rows g0,g1 -> f16x2 register arrays (fully unrolled: static indices)
  unsigned w0[64], w1[64];
  #pragma unroll
  for (int j = 0; j < 32; ++j) {
    float4 v = *(const float4*)&Whh[(size_t)g0 * H_ + j * 4];
    w0[2 * j]     = __builtin_bit_cast(unsigned, (f16x2){ (f16)v.x, (f16)v.y });
    w0[2 * j + 1] = __builtin_bit_cast(unsigned, (f16x2){ (f16)v.z, (f16)v.w });
    float4 u = *(const float4*)&Whh[(size_t)g1 * H_ + j * 4];
    w1[2 * j]     = __builtin_bit_cast(unsigned, (f16x2){ (f16)u.x, (f16)u.y });
    w1[2 * j + 1] = __builtin_bit_cast(unsigned, (f16x2){ (f16)u.z, (f16)u.w });
  }

  __shared__ __align__(16) unsigned hbuf[2][64];  // h as f16x2 words, dbuf
  __shared__ float gx[256];                       // sig(f), sig(o) exchange

  if (tid < 64) { hbuf[0][tid] = 0u; }
  float c = 0.0f;
  __syncthreads();

  auto rowof = [&](int t) -> size_t {
    int it = t;
    if (dir) it = (t < L) ? (L - 1 - t) : t;
    return ((size_t)(b * T_ + it)) * 1024 + (size_t)dir * 512;
  };

  // depth-2 xg prefetch, named slots (no runtime-indexed register arrays)
  f16 pa0, pa1, pb0, pb1;
  { size_t r = rowof(0); pa0 = xg[r + g0]; pa1 = xg[r + g1]; }
  { size_t r = rowof(1); pb0 = xg[r + g0]; pb1 = xg[r + g1]; }

#define STEP(t, P0, P1, HR, HW)                                              \
  {                                                                          \
    float xg0 = (float)(P0);                                                 \
    float xg1 = (float)(P1);                                                 \
    if ((t) + 2 < T_) {                                                      \
      size_t r2 = rowof((t) + 2);                                            \
      (P0) = xg[r2 + g0];                                                    \
      (P1) = xg[r2 + g1];                                                    \
    }                                                                        \
    float aA[4] = { xg0, 0.f, 0.f, 0.f };                                    \
    float aB[4] = { xg1, 0.f, 0.f, 0.f };                                    \
    _Pragma("unroll")                                                        \
    for (int j4 = 0; j4 < 16; ++j4) {                                        \
      uint4 hv = *(const uint4*)&(HR)[j4 * 4];                               \
      aA[0] = FDOT2(asf16x2(hv.x), asf16x2(w0[j4 * 4 + 0]), aA[0]);          \
      aB[0] = FDOT2(asf16x2(hv.x), asf16x2(w1[j4 * 4 + 0]), aB[0]);          \
      aA[1] = FDOT2(asf16x2(hv.y), asf16x2(w0[j4 * 4 + 1]), aA[1]);          \
      aB[1] = FDOT2(asf16x2(hv.y), asf16x2(w1[j4 * 4 + 1]), aB[1]);          \
      aA[2] = FDOT2(asf16x2(hv.z), asf16x2(w0[j4 * 4 + 2]), aA[2]);          \
      aB[2] = FDOT2(asf16x2(hv.z), asf16x2(w1[j4 * 4 + 2]), aB[2]);          \
      aA[3] = FDOT2(asf16x2(hv.w), asf16x2(w0[j4 * 4 + 3]), aA[3]);          \
      aB[3] = FDOT2(asf16x2(hv.w), asf16x2(w1[j4 * 4 + 3]), aB[3]);          \
    }                                                                        \
    float sumA = (aA[0] + aA[1]) + (aA[2] + aA[3]);                          \
    float sumB = (aB[0] + aB[1]) + (aB[2] + aB[3]);                          \
    float s0, s1;                                                            \
    if (tid >= 128) {      /* wave-uniform branch (waves 2,3) */             \
      s0 = fast_sig(sumA);               /* sig(f) */                        \
      s1 = fast_sig(sumB);               /* sig(o) */                        \
      gx[tid - 128] = s0;                                                    \
      gx[tid]       = s1;                                                    \
    } else {                                                                 \
      s0 = fast_sig(sumA);               /* sig(i) */                        \
      s1 = fast_tanh(sumB);              /* tanh(g) */                       \
    }                                                                        \
    BARRIER_LDS();                                                           \
    if (tid < 128) {                                                         \
      float fs = gx[tid];                                                    \
      float os = gx[128 + tid];                                              \
      c = fs * c + s0 * s1;                                                  \
      float hval = os * fast_tanh(c);                                        \
      ((unsigned short*)(HW))[tid] =                                         \
          __builtin_bit_cast(unsigned short, (f16)hval);                     \
      out[((size_t)(b * T_ + (t))) * 256 + dir * 128 + tid] = hval;          \
    }                                                                        \
    BARRIER_LDS();                                                           \
  }

  for (int tt = 0; tt < T_; tt += 2) {
    STEP(tt,     pa0, pa1, hbuf[0], hbuf[1]);
    STEP(tt + 1, pb0, pb1, hbuf[1], hbuf[0]);
  }
#undef STEP
}

// ---------------------------------------------------------------------------
extern "C" void kernel_launch(void* const* d_in, const int* in_sizes, int n_in,
                              void* d_out, int out_size, void* d_ws, size_t ws_size,
                              hipStream_t stream) {
  const float* x      = (const float*)d_in[0];
  const int*   lengths= (const int*)  d_in[1];
  const float* Wf_ih  = (const float*)d_in[2];
  const float* Wf_hh  = (const float*)d_in[3];
  const float* bf_ih  = (const float*)d_in[4];
  const float* bf_hh  = (const float*)d_in[5];
  const float* Wb_ih  = (const float*)d_in[6];
  const float* Wb_hh  = (const float*)d_in[7];
  const float* bb_ih  = (const float*)d_in[8];
  const float* bb_hh  = (const float*)d_in[9];
  float* out = (float*)d_out;
  f16*   xg  = (f16*)d_ws;   // needs B*T*1024*2 = 134,217,728 bytes

  (void)in_sizes; (void)n_in; (void)out_size; (void)ws_size;

  xg_gemm<<<dim3(8, 512), 256, 0, stream>>>(x, Wf_ih, Wb_ih,
                                            bf_ih, bf_hh, bb_ih, bb_hh, xg);
  birnn_rec<<<dim3(64), 256, 0, stream>>>(xg, Wf_hh, Wb_hh, lengths, out);
}